// Round 4
// baseline (117.279 us; speedup 1.0000x reference)
//
#include <hip/hip_runtime.h>

#define D_DIM 512
typedef float v2f __attribute__((ext_vector_type(2)));

__device__ __forceinline__ float flog2(float x) {
    return __builtin_amdgcn_logf(x);   // bare v_log_f32; inputs >= ~4e-6, no denormal wrapper
}

// out[i,j] = 1 - 0.5*S_ij + 0.5*(Ea_i + Eb_j),  S_ij = sum_d t*log2 t, t = a_id+b_jd
// Ea_i = sum_d a*log2 a (computed in-kernel from staged tiles, per z-half).
// Split-D x2 -> grid (32,32,2) = 2048 blocks = 8 blocks/CU. Both z-halves
// atomicAdd partials (out pre-zeroed); z==0 adds the constant 1.
constexpr int BN = 32, BM = 32;
constexpr int DK = 64;       // d per LDS chunk
constexpr int DSPLIT = 256;  // d per block
constexpr int RP = 68;       // floats/row: 64 d + 4 pad -> 272 B stride (16B-aligned,
                             // b128-friendly; B-reads 4-way banked but LDS pipe has slack)

__global__ __launch_bounds__(256)
void jsd_main_kernel(const float* __restrict__ a, const float* __restrict__ b,
                     float* __restrict__ out, int N, int M) {
    __shared__ __align__(16) float As[BN][RP];  // [row][d]
    __shared__ __align__(16) float Bs[BM][RP];
    __shared__ float eaRow[BN], ebCol[BM];

    const int tid = threadIdx.x;       // 256 = 16x16
    const int tx = tid & 15, ty = tid >> 4;
    const int rowBase = blockIdx.y * BN;
    const int colBase = blockIdx.x * BM;
    const int dStart  = blockIdx.z * DSPLIT;

    // entropy-slice assignment: row er, d-slice [es*8, es*8+8) of each DK chunk
    const int er = tid >> 3, es = tid & 7;

    v2f acc0 = {0.f, 0.f}, acc1 = {0.f, 0.f};   // acc{row r}{cols c0,c1}
    v2f ea2 = {0.f, 0.f}, eb2 = {0.f, 0.f};

    for (int dBase = dStart; dBase < dStart + DSPLIT; dBase += DK) {
        // ---- stage 32 rows x 64 d of A and B (float4 global -> b128 LDS)
#pragma unroll
        for (int rep = 0; rep < 2; ++rep) {
            int idx = tid + rep * 256;   // 0..511
            int r = idx >> 4;            // 0..31
            int q = idx & 15;            // 0..15
            float4 va = *(const float4*)(a + (size_t)(rowBase + r) * D_DIM + dBase + 4 * q);
            float4 vb = *(const float4*)(b + (size_t)(colBase + r) * D_DIM + dBase + 4 * q);
            *(float4*)&As[r][4 * q] = va;
            *(float4*)&Bs[r][4 * q] = vb;
        }
        __syncthreads();

        // ---- per-row entropy partials: 8 A-elems + 8 B-elems per thread
        {
            float4 xa0 = *(const float4*)&As[er][es * 8];
            float4 xa1 = *(const float4*)&As[er][es * 8 + 4];
            float4 xb0 = *(const float4*)&Bs[er][es * 8];
            float4 xb1 = *(const float4*)&Bs[er][es * 8 + 4];
            float av[8] = {xa0.x, xa0.y, xa0.z, xa0.w, xa1.x, xa1.y, xa1.z, xa1.w};
            float bv[8] = {xb0.x, xb0.y, xb0.z, xb0.w, xb1.x, xb1.y, xb1.z, xb1.w};
#pragma unroll
            for (int k = 0; k < 4; ++k) {
                v2f ta = {av[2 * k], av[2 * k + 1]};
                v2f la = {flog2(ta.x), flog2(ta.y)};
                ea2 = ta * la + ea2;
                v2f tb = {bv[2 * k], bv[2 * k + 1]};
                v2f lb = {flog2(tb.x), flog2(tb.y)};
                eb2 = tb * lb + eb2;
            }
        }

        // ---- main 2x2 microtile, packed fp32
        const float* Ar0 = &As[ty * 2 + 0][0];
        const float* Ar1 = &As[ty * 2 + 1][0];
        const float* Bc0 = &Bs[tx * 2 + 0][0];
        const float* Bc1 = &Bs[tx * 2 + 1][0];
#pragma unroll
        for (int dk = 0; dk < DK; dk += 4) {
            float4 A0 = *(const float4*)(Ar0 + dk);
            float4 A1 = *(const float4*)(Ar1 + dk);
            float4 B0 = *(const float4*)(Bc0 + dk);
            float4 B1 = *(const float4*)(Bc1 + dk);
            float a0v[4] = {A0.x, A0.y, A0.z, A0.w};
            float a1v[4] = {A1.x, A1.y, A1.z, A1.w};
            float b0v[4] = {B0.x, B0.y, B0.z, B0.w};
            float b1v[4] = {B1.x, B1.y, B1.z, B1.w};
#pragma unroll
            for (int k = 0; k < 4; ++k) {
                v2f bp = {b0v[k], b1v[k]};
                v2f t0 = v2f{a0v[k], a0v[k]} + bp;   // v_pk_add_f32
                v2f t1 = v2f{a1v[k], a1v[k]} + bp;
                v2f l0 = {flog2(t0.x), flog2(t0.y)};
                v2f l1 = {flog2(t1.x), flog2(t1.y)};
                acc0 = t0 * l0 + acc0;               // v_pk_fma_f32
                acc1 = t1 * l1 + acc1;
            }
        }
        __syncthreads();
    }

    // ---- reduce entropy partials across the 8 d-slices (lane groups of 8)
    float ea = ea2.x + ea2.y, eb = eb2.x + eb2.y;
#pragma unroll
    for (int off = 4; off > 0; off >>= 1) {
        ea += __shfl_down(ea, off, 8);
        eb += __shfl_down(eb, off, 8);
    }
    if (es == 0) { eaRow[er] = ea; ebCol[er] = eb; }
    __syncthreads();

    // ---- epilogue: atomic partial add (out pre-zeroed)
    const float base = (dStart == 0) ? 1.0f : 0.0f;
    const float eb0 = ebCol[tx * 2 + 0];
    const float eb1 = ebCol[tx * 2 + 1];
#pragma unroll
    for (int r = 0; r < 2; ++r) {
        int i = rowBase + ty * 2 + r;
        float eav = eaRow[ty * 2 + r];
        v2f accr = r ? acc1 : acc0;
        float v0 = base - 0.5f * accr.x + 0.5f * (eav + eb0);
        float v1 = base - 0.5f * accr.y + 0.5f * (eav + eb1);
        float* p = out + (size_t)i * M + colBase + tx * 2;
        atomicAdd(p + 0, v0);
        atomicAdd(p + 1, v1);
    }
}

extern "C" void kernel_launch(void* const* d_in, const int* in_sizes, int n_in,
                              void* d_out, int out_size, void* d_ws, size_t ws_size,
                              hipStream_t stream) {
    const float* a = (const float*)d_in[0];
    const float* b = (const float*)d_in[1];
    const int N = in_sizes[0] / D_DIM;   // 1024
    const int M = in_sizes[1] / D_DIM;   // 1024

    hipMemsetAsync(d_out, 0, (size_t)out_size * sizeof(float), stream);

    dim3 grid(M / BM, N / BN, D_DIM / DSPLIT);   // 32 x 32 x 2 = 2048 blocks
    jsd_main_kernel<<<grid, 256, 0, stream>>>(a, b, (float*)d_out, N, M);
}

// Round 5
// 114.866 us; speedup vs baseline: 1.0210x; 1.0210x over previous
//
#include <hip/hip_runtime.h>

#define D_DIM 512

__device__ __forceinline__ float flog2(float x) {
    return __builtin_amdgcn_logf(x);   // bare v_log_f32; inputs >= ~4e-6, no denormal wrapper
}

// ---- per-row sums: E[row] = sum_d x*log2(x). One wave per row, 4 rows/block.
__global__ __launch_bounds__(256)
void jsd_entropy_kernel(const float* __restrict__ a,
                        const float* __restrict__ b,
                        float* __restrict__ E, int N, int M) {
    int wave = threadIdx.x >> 6;
    int lane = threadIdx.x & 63;
    int row = blockIdx.x * 4 + wave;
    if (row >= N + M) return;
    const float* src = (row < N) ? (a + (size_t)row * D_DIM)
                                 : (b + (size_t)(row - N) * D_DIM);
    float s = 0.f;
#pragma unroll
    for (int d = lane; d < D_DIM; d += 64) {
        float x = src[d];
        s = fmaf(x, flog2(x), s);
    }
#pragma unroll
    for (int off = 32; off > 0; off >>= 1) s += __shfl_down(s, off, 64);
    if (lane == 0) E[row] = s;
}

// ---- main: out[i,j] = 1 - 0.5*S_ij + 0.5*(Ea[i] + Eb[j]),  S_ij = sum_d t*log2 t
// Split-D x2 -> grid (32,32,2) = 2048 blocks = 8 blocks/CU (32 waves/CU).
// Software-pipelined staging: chunk c+1's global loads are issued before
// computing chunk c, so the vmcnt wait at the next LDS-write finds data ready.
constexpr int BN = 32, BM = 32;
constexpr int DK = 64;       // d per LDS chunk (4 chunks per block)
constexpr int DSPLIT = 256;  // d per block
constexpr int NCHUNK = DSPLIT / DK;
constexpr int RP = 34;       // [d][row] pad: b64-aligned reads, tolerable write banking

__global__ __launch_bounds__(256, 8)
void jsd_main_kernel(const float* __restrict__ a, const float* __restrict__ b,
                     const float* __restrict__ Ea, const float* __restrict__ Eb,
                     float* __restrict__ out, int N, int M) {
    __shared__ float As[DK][RP];  // [d][row] transposed staging
    __shared__ float Bs[DK][RP];

    const int tid = threadIdx.x;       // 256 = 16x16
    const int tx = tid & 15, ty = tid >> 4;
    const int rowBase = blockIdx.y * BN;
    const int colBase = blockIdx.x * BM;
    const int dStart  = blockIdx.z * DSPLIT;

    // staging geometry (fixed per thread): rep 0 -> row r0, rep 1 -> row r0+16
    const int r0 = tid >> 4;           // 0..15
    const int q  = tid & 15;           // float4 index within 64-d chunk
    const float* aRow0 = a + (size_t)(rowBase + r0) * D_DIM + 4 * q;
    const float* aRow1 = aRow0 + (size_t)16 * D_DIM;
    const float* bRow0 = b + (size_t)(colBase + r0) * D_DIM + 4 * q;
    const float* bRow1 = bRow0 + (size_t)16 * D_DIM;

    float acc[2][2] = {};
    float4 pa0, pa1, pb0, pb1;

    // preload chunk 0
    pa0 = *(const float4*)(aRow0 + dStart);
    pa1 = *(const float4*)(aRow1 + dStart);
    pb0 = *(const float4*)(bRow0 + dStart);
    pb1 = *(const float4*)(bRow1 + dStart);

    for (int c = 0; c < NCHUNK; ++c) {
        // ---- commit prefetched regs to LDS (transposed)
        As[4 * q + 0][r0] = pa0.x; As[4 * q + 1][r0] = pa0.y;
        As[4 * q + 2][r0] = pa0.z; As[4 * q + 3][r0] = pa0.w;
        As[4 * q + 0][r0 + 16] = pa1.x; As[4 * q + 1][r0 + 16] = pa1.y;
        As[4 * q + 2][r0 + 16] = pa1.z; As[4 * q + 3][r0 + 16] = pa1.w;
        Bs[4 * q + 0][r0] = pb0.x; Bs[4 * q + 1][r0] = pb0.y;
        Bs[4 * q + 2][r0] = pb0.z; Bs[4 * q + 3][r0] = pb0.w;
        Bs[4 * q + 0][r0 + 16] = pb1.x; Bs[4 * q + 1][r0 + 16] = pb1.y;
        Bs[4 * q + 2][r0 + 16] = pb1.z; Bs[4 * q + 3][r0 + 16] = pb1.w;
        __syncthreads();

        // ---- issue next chunk's global loads (latency hidden by compute below)
        if (c + 1 < NCHUNK) {
            int dNext = dStart + (c + 1) * DK;
            pa0 = *(const float4*)(aRow0 + dNext);
            pa1 = *(const float4*)(aRow1 + dNext);
            pb0 = *(const float4*)(bRow0 + dNext);
            pb1 = *(const float4*)(bRow1 + dNext);
        }

        // ---- 2x2 microtile compute over DK d's
#pragma unroll 8
        for (int dk = 0; dk < DK; ++dk) {
            float2 av = *(const float2*)&As[dk][ty * 2];
            float2 bv = *(const float2*)&Bs[dk][tx * 2];
            float ar[2] = {av.x, av.y};
            float br[2] = {bv.x, bv.y};
#pragma unroll
            for (int r = 0; r < 2; ++r)
#pragma unroll
                for (int cc = 0; cc < 2; ++cc) {
                    float t = ar[r] + br[cc];
                    acc[r][cc] = fmaf(t, flog2(t), acc[r][cc]);
                }
        }
        __syncthreads();
    }

    // ---- epilogue: z==0 folds affine term; both halves atomicAdd (out pre-zeroed)
    const bool lead = (blockIdx.z == 0);
    const float eb0 = lead ? Eb[colBase + tx * 2 + 0] : 0.f;
    const float eb1 = lead ? Eb[colBase + tx * 2 + 1] : 0.f;
#pragma unroll
    for (int r = 0; r < 2; ++r) {
        int i = rowBase + ty * 2 + r;
        float ea = lead ? Ea[i] : 0.f;
        float v0 = -0.5f * acc[r][0] + (lead ? 1.0f + 0.5f * (ea + eb0) : 0.0f);
        float v1 = -0.5f * acc[r][1] + (lead ? 1.0f + 0.5f * (ea + eb1) : 0.0f);
        float* p = out + (size_t)i * M + colBase + tx * 2;
        atomicAdd(p + 0, v0);
        atomicAdd(p + 1, v1);
    }
}

extern "C" void kernel_launch(void* const* d_in, const int* in_sizes, int n_in,
                              void* d_out, int out_size, void* d_ws, size_t ws_size,
                              hipStream_t stream) {
    const float* a = (const float*)d_in[0];
    const float* b = (const float*)d_in[1];
    const int N = in_sizes[0] / D_DIM;   // 1024
    const int M = in_sizes[1] / D_DIM;   // 1024
    float* E = (float*)d_ws;             // Ea[0..N), Eb[N..N+M)

    hipMemsetAsync(d_out, 0, (size_t)out_size * sizeof(float), stream);
    jsd_entropy_kernel<<<(N + M + 3) / 4, 256, 0, stream>>>(a, b, E, N, M);

    dim3 grid(M / BM, N / BN, D_DIM / DSPLIT);   // 32 x 32 x 2 = 2048 blocks
    jsd_main_kernel<<<grid, 256, 0, stream>>>(a, b, E, E + N, (float*)d_out, N, M);
}